// Round 1
// baseline (1229.315 us; speedup 1.0000x reference)
//
#include <hip/hip_runtime.h>
#include <cstddef>

typedef unsigned short u16;
typedef _Float16 f16x8 __attribute__((ext_vector_type(8)));
typedef float f32x4 __attribute__((ext_vector_type(4)));

#define NB  8
#define NW  5
#define NS  5
#define NC  640
#define NHW 100
#define NQ  75
#define ND  500   // S*hw descriptors
#define NDP 512   // padded cols
#define NR  7500  // Q*hw rows
#define NRP 7552  // padded rows = 59*128
#define NRT 59

// workspace byte offsets
#define OFF_SUP   ((size_t)0)           // u16 [NB][NW][NDP][NC]  26,214,400 B
#define OFF_ABF   ((size_t)26214400)    // u16 [NB][NRP][NC]      77,332,480 B
#define OFF_QRN   ((size_t)103546880)   // f32 [NB][NRP]             241,664 B
#define OFF_PROTO ((size_t)103788544)   // f32 [NB][NW][NC]          102,400 B
// total ~99.1 MiB

__device__ __forceinline__ u16 f2h_bits(float x) {
  _Float16 h = (_Float16)x;
  return __builtin_bit_cast(u16, h);
}
__device__ __forceinline__ float h2f_bits(u16 u) {
  return (float)__builtin_bit_cast(_Float16, u);
}

__device__ __forceinline__ float block_sum(float v, float* sc, int t) {
  v += __shfl_xor(v, 32, 64);
  v += __shfl_xor(v, 16, 64);
  v += __shfl_xor(v, 8, 64);
  v += __shfl_xor(v, 4, 64);
  v += __shfl_xor(v, 2, 64);
  v += __shfl_xor(v, 1, 64);
  __syncthreads();
  if ((t & 63) == 0) sc[t >> 6] = v;
  __syncthreads();
  return sc[0] + sc[1] + sc[2] + sc[3];
}

// k1: per (b,w,32-c chunk): support per-channel norms over 500 descriptors,
// scaled fp16 transpose to sup2[b][w][d][c]; raw proto sums.
__global__ __launch_bounds__(256) void k1_sup(const float* __restrict__ xs,
                                              u16* __restrict__ sup2,
                                              float* __restrict__ proto_g) {
  const int cc = blockIdx.x, w = blockIdx.y, b = blockIdx.z;
  const int t = threadIdx.x;
  __shared__ u16 tile[NDP * 34];   // [d][c] pad 34 -> odd bank step, conflict-free
  __shared__ float rn[32];
  const size_t bw = (size_t)b * NW + w;
  const float* xbase = xs + bw * NS * NC * NHW;   // [S][C][hw]
  const int cb = cc * 32;

  {
    const int c = t >> 3, part = t & 7;   // 32 c x 8 partials
    float ss = 0.f, sm = 0.f;
    for (int j = part; j < ND; j += 8) {
      const int s = j / NHW, p = j % NHW;
      const float x = xbase[((size_t)s * NC + cb + c) * NHW + p];
      ss += x * x; sm += x;
    }
    ss += __shfl_xor(ss, 1, 64); ss += __shfl_xor(ss, 2, 64); ss += __shfl_xor(ss, 4, 64);
    sm += __shfl_xor(sm, 1, 64); sm += __shfl_xor(sm, 2, 64); sm += __shfl_xor(sm, 4, 64);
    if (part == 0) {
      rn[c] = 1.0f / sqrtf(ss);              // descriptor-axis norm (per b,w,c)
      proto_g[bw * NC + cb + c] = sm;        // raw sum; mean scale cancels in cosine
    }
  }
  __syncthreads();
  for (int idx = t; idx < NS * 32 * NHW; idx += 256) {  // coalesced in p
    const int p = idx % NHW, rest = idx / NHW;
    const int cl = rest & 31, s = rest >> 5;
    const float x = xbase[((size_t)s * NC + cb + cl) * NHW + p];
    tile[(s * NHW + p) * 34 + cl] = f2h_bits(x * rn[cl]);
  }
  if (t < 384) tile[(ND + (t >> 5)) * 34 + (t & 31)] = 0;   // zero pad rows 500..511
  __syncthreads();
  u16* obase = sup2 + bw * NDP * NC + cb;
  for (int idx = t; idx < NDP * 32; idx += 256) {
    const int cl = idx & 31, d = idx >> 5;
    obase[(size_t)d * NC + cl] = tile[d * 34 + cl];  // coalesced 64B segments
  }
}

// k2: per (b,q): transpose x_query[c][p] -> Abf[r][c] fp16 (unnormalized),
// per-row 1/norm, and the full cosine branch written into out.
__global__ __launch_bounds__(256) void k2_query(const float* __restrict__ xq,
                                                const float* __restrict__ proto_g,
                                                const float* __restrict__ rcosp,
                                                u16* __restrict__ Abf,
                                                float* __restrict__ qrn,
                                                float* __restrict__ out) {
  const int q = blockIdx.x, b = blockIdx.y;
  const int t = threadIdx.x;
  __shared__ u16 tile[128 * 102];   // [c_local][p], stride 102 -> odd bank step
  __shared__ float qm[NC];
  __shared__ float qs[NHW];
  __shared__ float sc[4];
  const float* xbase = xq + ((size_t)b * NQ + q) * NC * NHW;
  u16* abase = Abf + ((size_t)b * NRP + (size_t)q * NHW) * NC;

  for (int i = t; i < NC; i += 256) qm[i] = 0.f;
  if (t < NHW) qs[t] = 0.f;
  __syncthreads();

  for (int cc = 0; cc < 5; cc++) {          // 128-c chunks
    const float4* rb = (const float4*)(xbase + (size_t)cc * 128 * NHW);
    for (int i4 = t; i4 < 3200; i4 += 256) {  // fully coalesced float4 reads
      const float4 xv = rb[i4];
      const int e = i4 * 4;
      const int p = e % NHW, cl = e / NHW;    // 4|100 -> never crosses a channel
      atomicAdd(&qm[cc * 128 + cl], xv.x + xv.y + xv.z + xv.w);
      atomicAdd(&qs[p], xv.x * xv.x);
      atomicAdd(&qs[p + 1], xv.y * xv.y);
      atomicAdd(&qs[p + 2], xv.z * xv.z);
      atomicAdd(&qs[p + 3], xv.w * xv.w);
      const unsigned lo = (unsigned)f2h_bits(xv.x) | ((unsigned)f2h_bits(xv.y) << 16);
      const unsigned hi = (unsigned)f2h_bits(xv.z) | ((unsigned)f2h_bits(xv.w) << 16);
      unsigned* tw = (unsigned*)&tile[cl * 102 + p];
      tw[0] = lo; tw[1] = hi;
    }
    __syncthreads();
    const int c0 = t & 63, pr = t >> 6;
    for (int p = pr; p < NHW; p += 4) {       // coalesced 128B fp16 writes
      abase[(size_t)p * NC + cc * 128 + c0] = tile[c0 * 102 + p];
      abase[(size_t)p * NC + cc * 128 + c0 + 64] = tile[(c0 + 64) * 102 + p];
    }
    __syncthreads();
  }
  if (t < NHW) qrn[(size_t)b * NRP + q * NHW + t] = 1.0f / sqrtf(qs[t]);

  // cosine branch: qn.pn = (qm.proto)/(|qm||proto|) -- mean scales cancel
  float part = 0.f;
  for (int c = t; c < NC; c += 256) part += qm[c] * qm[c];
  const float qq = block_sum(part, sc, t);
  const float rcos = rcosp[0];
  for (int w = 0; w < NW; w++) {
    const float* pr_ = proto_g + ((size_t)b * NW + w) * NC;
    float dp = 0.f, pp = 0.f;
    for (int c = t; c < NC; c += 256) { const float pv = pr_[c]; dp += qm[c] * pv; pp += pv * pv; }
    dp = block_sum(dp, sc, t);
    pp = block_sum(pp, sc, t);
    if (t == 0) out[((size_t)b * NQ + q) * NW + w] = rcos * dp / sqrtf(qq * pp);
  }
  if (q == 0) {   // zero A pad rows [7500,7552) for this b
    u16* pz = Abf + ((size_t)b * NRP + NR) * NC;
    for (int i = t; i < (NRP - NR) * NC; i += 256) pz[i] = 0;
  }
}

// k4: per (b,w,128-row tile): 4 x [128x128x640 fp16 MFMA GEMM -> LDS dump ->
// streaming top-5 per row], then scale+atomicAdd into out.
__global__ __launch_bounds__(256) void k4_dn4(const u16* __restrict__ Abf,
                                              const u16* __restrict__ sup2,
                                              const float* __restrict__ qrn,
                                              const float* __restrict__ rdn4p,
                                              const int* __restrict__ nkp,
                                              float* __restrict__ out) {
  const int rt = blockIdx.x, w = blockIdx.y, b = blockIdx.z;
  const int t = threadIdx.x;
  const int lane = t & 63, wid = t >> 6;
  const int m = lane & 15, quad = lane >> 4;
  const int wx = wid & 1, wy = wid >> 1;

  __shared__ __align__(16) char smem[33792];
  u16* lds_a = (u16*)smem;            // [128][40] fp16, stride 40 (80B, 16B-mult)
  u16* lds_b = (u16*)(smem + 10240);  // [128][40]
  u16* cd    = (u16*)smem;            // [128 cols][132 rows] fp16 dump (aliases staging)
  float* t5b = (float*)smem;          // [128][5] final merge (aliases)

  const u16* Ab = Abf + ((size_t)b * NRP + (size_t)rt * 128) * NC;
  const u16* Bb = sup2 + ((size_t)b * NW + w) * NDP * NC;

  float t5[5] = {-3e38f, -3e38f, -3e38f, -3e38f, -3e38f};  // sorted ascending
  const int half = t >> 7, rown = t & 127;
  const int c8 = (t & 3) * 8;
  const int rr = t >> 2;

  for (int ct = 0; ct < 4; ct++) {
    f32x4 acc[4][4];
#pragma unroll
    for (int mt = 0; mt < 4; mt++)
#pragma unroll
      for (int nt = 0; nt < 4; nt++)
        acc[mt][nt] = (f32x4){0.f, 0.f, 0.f, 0.f};
    const u16* Bc = Bb + (size_t)ct * 128 * NC;

    for (int k0 = 0; k0 < NC; k0 += 32) {
      __syncthreads();  // also guards staging vs prior chunk's cd scan
      const uint4 a0 = *(const uint4*)(Ab + (size_t)rr * NC + k0 + c8);
      const uint4 a1 = *(const uint4*)(Ab + ((size_t)rr + 64) * NC + k0 + c8);
      const uint4 b0 = *(const uint4*)(Bc + (size_t)rr * NC + k0 + c8);
      const uint4 b1 = *(const uint4*)(Bc + ((size_t)rr + 64) * NC + k0 + c8);
      *(uint4*)&lds_a[rr * 40 + c8] = a0;
      *(uint4*)&lds_a[(rr + 64) * 40 + c8] = a1;
      *(uint4*)&lds_b[rr * 40 + c8] = b0;
      *(uint4*)&lds_b[(rr + 64) * 40 + c8] = b1;
      __syncthreads();
      f16x8 af[4], bfr[4];
#pragma unroll
      for (int mt = 0; mt < 4; mt++)
        af[mt] = *(const f16x8*)&lds_a[(wy * 64 + mt * 16 + m) * 40 + quad * 8];
#pragma unroll
      for (int nt = 0; nt < 4; nt++)
        bfr[nt] = *(const f16x8*)&lds_b[(wx * 64 + nt * 16 + m) * 40 + quad * 8];
#pragma unroll
      for (int mt = 0; mt < 4; mt++)
#pragma unroll
        for (int nt = 0; nt < 4; nt++)
          acc[mt][nt] = __builtin_amdgcn_mfma_f32_16x16x32_f16(af[mt], bfr[nt], acc[mt][nt], 0, 0, 0);
    }
    __syncthreads();
    // dump C col-major fp16: C/D layout col=lane&15, row=quad*4+reg
#pragma unroll
    for (int mt = 0; mt < 4; mt++)
#pragma unroll
      for (int nt = 0; nt < 4; nt++) {
        const int rb = wy * 64 + mt * 16 + quad * 4;
        const int cl = wx * 64 + nt * 16 + m;
        const unsigned lo = (unsigned)f2h_bits(acc[mt][nt].x) | ((unsigned)f2h_bits(acc[mt][nt].y) << 16);
        const unsigned hi = (unsigned)f2h_bits(acc[mt][nt].z) | ((unsigned)f2h_bits(acc[mt][nt].w) << 16);
        unsigned* dst = (unsigned*)&cd[cl * 132 + rb];
        dst[0] = lo; dst[1] = hi;
      }
    __syncthreads();
    // streaming top-5: 2 threads per row, 64 cols each; conflict-free scan
    const int dbase = ct * 128 + half * 64;
    for (int j = 0; j < 64; j++) {
      const int d = dbase + j;
      if (d >= ND) break;   // wave-uniform
      const float v = h2f_bits(cd[(half * 64 + j) * 132 + rown]);
      if (v > t5[0]) {
        t5[0] = v; float tmp;
        if (t5[0] > t5[1]) { tmp = t5[0]; t5[0] = t5[1]; t5[1] = tmp; }
        if (t5[1] > t5[2]) { tmp = t5[1]; t5[1] = t5[2]; t5[2] = tmp; }
        if (t5[2] > t5[3]) { tmp = t5[2]; t5[2] = t5[3]; t5[3] = tmp; }
        if (t5[3] > t5[4]) { tmp = t5[3]; t5[3] = t5[4]; t5[4] = tmp; }
      }
    }
  }
  __syncthreads();
  if (half == 1) {
#pragma unroll
    for (int i = 0; i < 5; i++) t5b[rown * 5 + i] = t5[i];
  }
  __syncthreads();
  if (half == 0) {
#pragma unroll
    for (int i = 0; i < 5; i++) {
      const float v = t5b[rown * 5 + i];
      if (v > t5[0]) {
        t5[0] = v; float tmp;
        if (t5[0] > t5[1]) { tmp = t5[0]; t5[0] = t5[1]; t5[1] = tmp; }
        if (t5[1] > t5[2]) { tmp = t5[1]; t5[1] = t5[2]; t5[2] = tmp; }
        if (t5[2] > t5[3]) { tmp = t5[2]; t5[2] = t5[3]; t5[3] = tmp; }
        if (t5[3] > t5[4]) { tmp = t5[3]; t5[3] = t5[4]; t5[4] = tmp; }
      }
    }
    const int r = rt * 128 + rown;
    if (r < NR) {
      const float s = t5[0] + t5[1] + t5[2] + t5[3] + t5[4];
      // fold per-row 1/|qd| (positive scale commutes with top-k), r_dn4, 1/k
      const float contrib = s * qrn[(size_t)b * NRP + r] * rdn4p[0] / (float)nkp[0];
      const int qi = r / NHW;
      atomicAdd(&out[((size_t)b * NQ + qi) * NW + w], contrib);
    }
  }
}

extern "C" void kernel_launch(void* const* d_in, const int* in_sizes, int n_in,
                              void* d_out, int out_size, void* d_ws, size_t ws_size,
                              hipStream_t stream) {
  (void)in_sizes; (void)n_in; (void)out_size; (void)ws_size;
  const float* xs   = (const float*)d_in[0];
  const float* xq   = (const float*)d_in[1];
  const float* rcos = (const float*)d_in[2];
  const float* rdn4 = (const float*)d_in[3];
  const int*   nk   = (const int*)d_in[4];
  float* out = (float*)d_out;
  char* ws = (char*)d_ws;
  u16*   sup2  = (u16*)(ws + OFF_SUP);
  u16*   Abf   = (u16*)(ws + OFF_ABF);
  float* qrn   = (float*)(ws + OFF_QRN);
  float* proto = (float*)(ws + OFF_PROTO);

  k1_sup <<<dim3(20, NW, NB), dim3(256), 0, stream>>>(xs, sup2, proto);
  k2_query<<<dim3(NQ, NB),    dim3(256), 0, stream>>>(xq, proto, rcos, Abf, qrn, out);
  k4_dn4 <<<dim3(NRT, NW, NB), dim3(256), 0, stream>>>(Abf, sup2, qrn, rdn4, nk, out);
}